// Round 5
// baseline (276.485 us; speedup 1.0000x reference)
//
#include <hip/hip_runtime.h>

// EarlyRewardLoss, N=4096, T=365, C=32.
// R5: decouple the sequential scan from the gather (R1/R3/R4 all tied at
// ~83 us kernel time despite totally different memory strategies ->
// bottleneck is the per-row block structure: dependent shfl-scan chain +
// barriers serialized inside each short-lived block, not bytes).
// Kernel 1 (tiny): wave-per-row cumprod scan -> Pt[n,t] (+EPS/T folded)
//   into d_ws. ~12 MB traffic. Also zeroes out[0].
// Kernel 2 (hot): pure grid-stride gather-reduce over 1.495M (n,t) pairs.
//   6 independent yt/Pt loads + 6 independent 16B logp gathers issued
//   back-to-back per thread (max MLP), branchless element select, per-block
//   reduce, one atomicAdd per block. No scan, no data staging, max latency
//   tolerance.

constexpr int   T_DIM      = 365;
constexpr int   C_DIM      = 32;
constexpr int   N_DIM      = 4096;
constexpr int   M_TOT      = N_DIM * T_DIM;        // 1,495,040
constexpr float EPS_OVER_T = 10.0f / 365.0f;
constexpr int   G2         = 1024;                 // kernel2 grid
constexpr int   STRIDE     = G2 * 256;             // 262,144 threads
constexpr int   UNROLL     = 6;                    // ceil(M/STRIDE) = 6

// ---------------- kernel 1: Pt scan ----------------
__global__ __launch_bounds__(256)
void pt_kernel(const float* __restrict__ ps,   // [N,T]
               float* __restrict__ pt,         // [N,T] (ws)
               float* __restrict__ out)        // zero the scalar output
{
    if (blockIdx.x == 0 && threadIdx.x == 0) out[0] = 0.0f;

    const int lane = threadIdx.x & 63;
    const int wave = threadIdx.x >> 6;
    const int row  = blockIdx.x * 4 + wave;

    const float* psr = ps + (size_t)row * T_DIM;
    float*       ptr = pt + (size_t)row * T_DIM;

    float carry = 1.0f;
    #pragma unroll
    for (int k = 0; k < 6; ++k) {
        const int t = k * 64 + lane;
        float d;
        if (t < T_DIM - 1)       d = psr[t + 1];
        else if (t == T_DIM - 1) d = 1.0f;
        else                     d = 0.0f;      // pad: m=1, no scan effect

        float s = 1.0f - d;
        #pragma unroll
        for (int off = 1; off < 64; off <<= 1) {
            const float o = __shfl_up(s, off);
            if (lane >= off) s *= o;
        }
        float e = __shfl_up(s, 1);
        if (lane == 0) e = 1.0f;

        if (t < T_DIM) ptr[t] = d * carry * e + EPS_OVER_T;
        carry *= __shfl(s, 63);
    }
}

// ---------------- kernel 2: gather + reduce ----------------
__device__ __forceinline__ float sel4(float4 v, unsigned d) {
    float r = (d == 1u) ? v.y : v.x;
    r       = (d == 2u) ? v.z : r;
    r       = (d == 3u) ? v.w : r;
    return r;
}

__global__ __launch_bounds__(256)
void loss_kernel(const float* __restrict__ logp,  // [N,T,C]
                 const float* __restrict__ pt,    // [N,T] (ws)
                 const int*   __restrict__ yt,    // [N,T]
                 float* __restrict__ out)
{
    const int tid0 = blockIdx.x * 256 + threadIdx.x;

    int    y[UNROLL];
    float  p[UNROLL];
    float4 v[UNROLL];   // scalarized by full unroll; indices all constant
    bool   ok[UNROLL];

    // phase 1: independent yt + Pt loads
    #pragma unroll
    for (int j = 0; j < UNROLL; ++j) {
        const int idx = tid0 + j * STRIDE;
        ok[j] = (idx < M_TOT);
        y[j] = 0; p[j] = 0.0f;
        if (ok[j]) { y[j] = yt[idx]; p[j] = pt[idx]; }
    }
    // phase 2: independent 16B gathers (aligned float4 containing logp[.,y])
    #pragma unroll
    for (int j = 0; j < UNROLL; ++j) {
        const int idx = tid0 + j * STRIDE;
        if (ok[j]) v[j] = *(const float4*)(logp + (size_t)idx * C_DIM + (y[j] & ~3));
    }
    // phase 3: accumulate
    float cl = 0.0f, er = 0.0f;
    #pragma unroll
    for (int j = 0; j < UNROLL; ++j) {
        if (ok[j]) {
            const int   idx = tid0 + j * STRIDE;
            const int   n   = idx / T_DIM;            // magic-mul div
            const int   t   = idx - n * T_DIM;
            const float lp  = sel4(v[j], (unsigned)(y[j] & 3));
            const float w   = 1.0f - (float)t * (1.0f / T_DIM);
            cl += lp * p[j];
            er += p[j] * __expf(lp) * w;
        }
    }

    // block reduction: wave shfl -> LDS -> one atomic per block
    float s = cl + er;
    #pragma unroll
    for (int off = 32; off > 0; off >>= 1) s += __shfl_xor(s, off);

    __shared__ float w4[4];
    const int lane = threadIdx.x & 63;
    const int wv   = threadIdx.x >> 6;
    if (lane == 0) w4[wv] = s;
    __syncthreads();
    if (threadIdx.x == 0) {
        const float v4 = w4[0] + w4[1] + w4[2] + w4[3];
        atomicAdd(out, v4 * (-0.5f / (float)N_DIM));
    }
}

extern "C" void kernel_launch(void* const* d_in, const int* in_sizes, int n_in,
                              void* d_out, int out_size, void* d_ws, size_t ws_size,
                              hipStream_t stream) {
    const float* logp = (const float*)d_in[0];
    const float* ps   = (const float*)d_in[1];
    const int*   yt   = (const int*)d_in[2];
    float* out = (float*)d_out;
    float* pt  = (float*)d_ws;   // N*T floats = 5.98 MB

    pt_kernel<<<N_DIM / 4, 256, 0, stream>>>(ps, pt, out);
    loss_kernel<<<G2, 256, 0, stream>>>(logp, pt, yt, out);
}

// Round 6
// 274.896 us; speedup vs baseline: 1.0058x; 1.0058x over previous
//
#include <hip/hip_runtime.h>

// EarlyRewardLoss, N=4096, T=365, C=32.
// R6: fill-shaped streaming kernel. R1/R3/R4/R5 (four different memory
// strategies) all tied at ~83-92 us kernel time (~2.4 TB/s) while the
// harness fill hits 6.8 TB/s. Remaining structural difference: LDS/scan
// coupling or ws round-trips inside the hot kernel. R6's hot kernel is
// shaped exactly like the fill: flat grid, each thread streams 8 float4
// of logp (stride = whole-grid), two tiny 8-way-broadcast loads (yt, pt)
// per float4, conditional contribution, register-only block reduce.
// No LDS data staging, no scan, no syncthreads between load phases.
// Kernel 1 (pt_kernel, ~4us): wave-per-row cumprod scan -> Pt (+EPS/T).
// Kernel 3 (reduce): 1 block sums 5840 block partials. No atomics.

constexpr int   T_DIM      = 365;
constexpr int   C_DIM      = 32;
constexpr int   N_DIM      = 4096;
constexpr int   M_TOT      = N_DIM * T_DIM;        // 1,495,040 (n,t) pairs
constexpr int   F4_TOT     = M_TOT * (C_DIM / 4);  // 11,960,320 float4
constexpr float EPS_OVER_T = 10.0f / 365.0f;
constexpr int   BLOCKS2    = M_TOT / 256;          // 5840 (exact)

// ---------------- kernel 1: Pt scan ----------------
__global__ __launch_bounds__(256)
void pt_kernel(const float* __restrict__ ps,   // [N,T]
               float* __restrict__ pt)         // [N,T] (ws)
{
    const int lane = threadIdx.x & 63;
    const int wave = threadIdx.x >> 6;
    const int row  = blockIdx.x * 4 + wave;

    const float* psr = ps + (size_t)row * T_DIM;
    float*       ptr = pt + (size_t)row * T_DIM;

    float carry = 1.0f;
    #pragma unroll
    for (int k = 0; k < 6; ++k) {
        const int t = k * 64 + lane;
        float d;
        if (t < T_DIM - 1)       d = psr[t + 1];
        else if (t == T_DIM - 1) d = 1.0f;
        else                     d = 0.0f;      // pad: m=1, no scan effect

        float s = 1.0f - d;
        #pragma unroll
        for (int off = 1; off < 64; off <<= 1) {
            const float o = __shfl_up(s, off);
            if (lane >= off) s *= o;
        }
        float e = __shfl_up(s, 1);
        if (lane == 0) e = 1.0f;

        if (t < T_DIM) ptr[t] = d * carry * e + EPS_OVER_T;
        carry *= __shfl(s, 63);
    }
}

// ---------------- kernel 2: fill-shaped stream ----------------
__device__ __forceinline__ float sel4(float4 v, unsigned d) {
    float r = (d == 1u) ? v.y : v.x;
    r       = (d == 2u) ? v.z : r;
    r       = (d == 3u) ? v.w : r;
    return r;
}

__global__ __launch_bounds__(256)
void loss_kernel(const float4* __restrict__ lp4,  // [N*T*8] float4 view
                 const float*  __restrict__ pt,   // [N,T] (ws)
                 const int*    __restrict__ yt,   // [N,T]
                 float* __restrict__ partial)     // [BLOCKS2]
{
    const int tid0 = blockIdx.x * 256 + threadIdx.x;   // 0 .. M_TOT-1

    float acc = 0.0f;
    #pragma unroll
    for (int j = 0; j < 8; ++j) {
        const int g   = tid0 + j * M_TOT;   // float4 index, contiguous sweep
        const int idx = g >> 3;             // (n,t) pair
        const int c0  = (g & 7) << 2;       // first class in this float4

        const int    y = yt[idx];           // 8 lanes share -> broadcast
        const float  p = pt[idx];
        const float4 v = lp4[g];            // perfectly coalesced 16B

        const unsigned d = (unsigned)(y - c0);
        if (d < 4u) {
            const float lp = sel4(v, d);
            const int   n  = idx / T_DIM;
            const int   t  = idx - n * T_DIM;
            const float w  = 1.0f - (float)t * (1.0f / T_DIM);
            acc += p * (lp + __expf(lp) * w);
        }
    }

    // block reduction, register/LDS only
    #pragma unroll
    for (int off = 32; off > 0; off >>= 1) acc += __shfl_xor(acc, off);

    __shared__ float w4[4];
    const int lane = threadIdx.x & 63;
    const int wv   = threadIdx.x >> 6;
    if (lane == 0) w4[wv] = acc;
    __syncthreads();
    if (threadIdx.x == 0)
        partial[blockIdx.x] = w4[0] + w4[1] + w4[2] + w4[3];
}

// ---------------- kernel 3: final reduce ----------------
__global__ __launch_bounds__(256)
void reduce_kernel(const float* __restrict__ partial, float* __restrict__ out)
{
    const int tid = threadIdx.x;
    float s = 0.0f;
    for (int j = tid; j < BLOCKS2; j += 256) s += partial[j];

    #pragma unroll
    for (int off = 32; off > 0; off >>= 1) s += __shfl_xor(s, off);

    __shared__ float w[4];
    if ((tid & 63) == 0) w[tid >> 6] = s;
    __syncthreads();
    if (tid == 0) out[0] = (w[0] + w[1] + w[2] + w[3]) * (-0.5f / (float)N_DIM);
}

extern "C" void kernel_launch(void* const* d_in, const int* in_sizes, int n_in,
                              void* d_out, int out_size, void* d_ws, size_t ws_size,
                              hipStream_t stream) {
    const float* logp = (const float*)d_in[0];
    const float* ps   = (const float*)d_in[1];
    const int*   yt   = (const int*)d_in[2];
    float* out     = (float*)d_out;
    float* pt      = (float*)d_ws;             // M_TOT floats = 5.98 MB
    float* partial = pt + M_TOT;               // BLOCKS2 floats

    pt_kernel<<<N_DIM / 4, 256, 0, stream>>>(ps, pt);
    loss_kernel<<<BLOCKS2, 256, 0, stream>>>((const float4*)logp, pt, yt, partial);
    reduce_kernel<<<1, 256, 0, stream>>>(partial, out);
}